// Round 1
// baseline (847.167 us; speedup 1.0000x reference)
//
#include <hip/hip_runtime.h>

// DotProductAttention: B=4,H=16,S=2048,D=128, fp32 in/out, bf16 MFMA compute.
// Flash-attention forward: per block 128 q-rows (4 waves x 32), K-tiles of 64.

#define Sdim 2048
#define Ddim 128
constexpr int BLOCK_M = 128;
constexpr int BLOCK_N = 64;

typedef __attribute__((ext_vector_type(8))) short short8;
typedef __attribute__((ext_vector_type(4))) short short4v;
typedef __attribute__((ext_vector_type(4))) float floatx4;

__device__ __forceinline__ short f2bf(float f) {
  union { float f; unsigned u; } v; v.f = f;
  return (short)((v.u + 0x7FFFu + ((v.u >> 16) & 1u)) >> 16);  // RNE
}

__device__ __forceinline__ float red16_max(float x) {
  x = fmaxf(x, __shfl_xor(x, 1));
  x = fmaxf(x, __shfl_xor(x, 2));
  x = fmaxf(x, __shfl_xor(x, 4));
  x = fmaxf(x, __shfl_xor(x, 8));
  return x;
}
__device__ __forceinline__ float red16_sum(float x) {
  x += __shfl_xor(x, 1);
  x += __shfl_xor(x, 2);
  x += __shfl_xor(x, 4);
  x += __shfl_xor(x, 8);
  return x;
}

__launch_bounds__(256, 2)
__global__ void attn_fwd(const float* __restrict__ Qg,
                         const float* __restrict__ Kg,
                         const float* __restrict__ Vg,
                         float* __restrict__ Og) {
  // K frags: [nt(4)][kts(4)][slot(64)][j(8)]  (B-operand of QK^T)
  __shared__ short sKf[4 * 4 * 64 * 8];
  // V frags: [kt(2)][dt(8)][slot(64)][j(8)]   (B-operand of P*V)
  __shared__ short sVf[2 * 8 * 64 * 8];
  // P frags: [wave(4)][mt(2)][kt(2)][slot(64)][j(8)] (A-operand of P*V)
  __shared__ short sP[4 * 2 * 2 * 64 * 8];

  const int tid  = threadIdx.x;
  const int wv   = tid >> 6;
  const int lane = tid & 63;
  const int qd   = lane >> 4;   // quad 0..3
  const int cl   = lane & 15;   // col  0..15

  const int bh = blockIdx.y;
  const int q0 = blockIdx.x * BLOCK_M + wv * 32;
  const float* Qb = Qg + (size_t)bh * Sdim * Ddim;
  const float* Kb = Kg + (size_t)bh * Sdim * Ddim;
  const float* Vb = Vg + (size_t)bh * Sdim * Ddim;
  float*       Ob = Og + (size_t)bh * Sdim * Ddim;

  // ---- Q fragments (A-operand): lane holds Q[m=cl][kts*32 + qd*8 + j] ----
  short8 qf[2][4];
#pragma unroll
  for (int mt = 0; mt < 2; ++mt) {
    const floatx4* qp = (const floatx4*)(Qb + (q0 + mt * 16 + cl) * Ddim);
#pragma unroll
    for (int kts = 0; kts < 4; ++kts) {
      floatx4 a = qp[kts * 8 + qd * 2];
      floatx4 b = qp[kts * 8 + qd * 2 + 1];
      short8 s;
      s[0] = f2bf(a[0]); s[1] = f2bf(a[1]); s[2] = f2bf(a[2]); s[3] = f2bf(a[3]);
      s[4] = f2bf(b[0]); s[5] = f2bf(b[1]); s[6] = f2bf(b[2]); s[7] = f2bf(b[3]);
      qf[mt][kts] = s;
    }
  }

  floatx4 o_acc[2][8];
#pragma unroll
  for (int mt = 0; mt < 2; ++mt)
#pragma unroll
    for (int dt = 0; dt < 8; ++dt)
      o_acc[mt][dt] = (floatx4){0.f, 0.f, 0.f, 0.f};
  float m_run[2][4], l_run[2][4];
#pragma unroll
  for (int mt = 0; mt < 2; ++mt)
#pragma unroll
    for (int r = 0; r < 4; ++r) { m_run[mt][r] = -3.0e38f; l_run[mt][r] = 0.f; }

  constexpr float LSC = 0.08838834764831845f * 1.4426950408889634f;  // 1/sqrt(128)*log2(e)

  // staging index precompute
  const int kf4  = tid & 31;          // float4 index within K row
  const int krb  = tid >> 5;          // row base 0..7
  const int kkts = kf4 >> 3;
  const int kqq  = (kf4 >> 1) & 3;
  const int kj0  = (kf4 & 1) * 4;
  const int vd    = tid & 127;        // d column for V staging
  const int vhalf = tid >> 7;
  const int vdt   = vd >> 4;
  const int vc2   = (vd & 15) ^ (2 * (vdt & 3));  // bank swizzle

  for (int n0 = 0; n0 < Sdim; n0 += BLOCK_N) {
    // ---- stage K tile into fragment order ----
#pragma unroll
    for (int it = 0; it < 8; ++it) {
      int n = it * 8 + krb;
      floatx4 kv = *(const floatx4*)(Kb + (n0 + n) * Ddim + kf4 * 4);
      int nt = n >> 4;
      int cc = (n & 15) ^ (2 * kkts);  // swizzle must match reader
      short4v s;
      s[0] = f2bf(kv[0]); s[1] = f2bf(kv[1]); s[2] = f2bf(kv[2]); s[3] = f2bf(kv[3]);
      *(short4v*)&sKf[((nt * 4 + kkts) * 64 + kqq * 16 + cc) * 8 + kj0] = s;
    }
    // ---- stage V tile transposed into fragment order ----
#pragma unroll
    for (int it = 0; it < 8; ++it) {
      int n4 = it * 2 + vhalf;                 // group of 4 consecutive n
      int kt = n4 >> 3, qq = (n4 >> 1) & 3, j0 = (n4 & 1) * 4;
      const float* vp = Vb + (n0 + n4 * 4) * Ddim + vd;
      float v0 = vp[0], v1 = vp[Ddim], v2 = vp[2 * Ddim], v3 = vp[3 * Ddim];
      short4v s;
      s[0] = f2bf(v0); s[1] = f2bf(v1); s[2] = f2bf(v2); s[3] = f2bf(v3);
      *(short4v*)&sVf[((kt * 8 + vdt) * 64 + qq * 16 + vc2) * 8 + j0] = s;
    }
    __syncthreads();

    // ---- S = Q K^T ----
    floatx4 s_acc[2][4];
#pragma unroll
    for (int mt = 0; mt < 2; ++mt)
#pragma unroll
      for (int nt = 0; nt < 4; ++nt) s_acc[mt][nt] = (floatx4){0.f, 0.f, 0.f, 0.f};
#pragma unroll
    for (int kts = 0; kts < 4; ++kts) {
      int slot = qd * 16 + (cl ^ (2 * kts));
      short8 kfr[4];
#pragma unroll
      for (int nt = 0; nt < 4; ++nt)
        kfr[nt] = *(const short8*)&sKf[((nt * 4 + kts) * 64 + slot) * 8];
#pragma unroll
      for (int nt = 0; nt < 4; ++nt)
#pragma unroll
        for (int mt = 0; mt < 2; ++mt)
          s_acc[mt][nt] = __builtin_amdgcn_mfma_f32_16x16x32_bf16(
              qf[mt][kts], kfr[nt], s_acc[mt][nt], 0, 0, 0);
    }

    // ---- online softmax (rows = mt*16 + 4*qd + r, cols across cl x nt) ----
#pragma unroll
    for (int mt = 0; mt < 2; ++mt) {
#pragma unroll
      for (int r = 0; r < 4; ++r) {
        float mx = fmaxf(fmaxf(s_acc[mt][0][r], s_acc[mt][1][r]),
                         fmaxf(s_acc[mt][2][r], s_acc[mt][3][r]));
        mx = red16_max(mx);
        float mnew  = fmaxf(m_run[mt][r], mx);
        float alpha = __builtin_amdgcn_exp2f((m_run[mt][r] - mnew) * LSC);
        float rs = 0.f;
#pragma unroll
        for (int nt = 0; nt < 4; ++nt) {
          float p = __builtin_amdgcn_exp2f((s_acc[mt][nt][r] - mnew) * LSC);
          s_acc[mt][nt][r] = p;
          rs += p;
        }
        rs = red16_sum(rs);
        l_run[mt][r] = l_run[mt][r] * alpha + rs;
        m_run[mt][r] = mnew;
#pragma unroll
        for (int dt = 0; dt < 8; ++dt) o_acc[mt][dt][r] *= alpha;
        // write P element (m = mt*16+4qd+r, n = nt*16+cl) into A-frag order
#pragma unroll
        for (int nt = 0; nt < 4; ++nt) {
          int q2 = (nt & 1) * 2 + (cl >> 3);
          sP[((wv * 4 + mt * 2 + (nt >> 1)) * 64 + q2 * 16 + 4 * qd + r) * 8 + (cl & 7)] =
              f2bf(s_acc[mt][nt][r]);
        }
      }
    }

    // ---- O += P V ----
#pragma unroll
    for (int kt = 0; kt < 2; ++kt) {
      short8 pf[2];
#pragma unroll
      for (int mt = 0; mt < 2; ++mt)
        pf[mt] = *(const short8*)&sP[((wv * 4 + mt * 2 + kt) * 64 + lane) * 8];
#pragma unroll
      for (int dt = 0; dt < 8; ++dt) {
        short8 vf = *(const short8*)&sVf[((kt * 8 + dt) * 64 + qd * 16 +
                                          (cl ^ (2 * (dt & 3)))) * 8];
#pragma unroll
        for (int mt = 0; mt < 2; ++mt)
          o_acc[mt][dt] = __builtin_amdgcn_mfma_f32_16x16x32_bf16(
              pf[mt], vf, o_acc[mt][dt], 0, 0, 0);
      }
    }
    __syncthreads();
  }

  // ---- epilogue: normalize by l and store fp32 ----
#pragma unroll
  for (int mt = 0; mt < 2; ++mt) {
#pragma unroll
    for (int r = 0; r < 4; ++r) {
      float inv = 1.0f / l_run[mt][r];
      float* orow = Ob + (q0 + mt * 16 + 4 * qd + r) * Ddim + cl;
#pragma unroll
      for (int dt = 0; dt < 8; ++dt)
        orow[dt * 16] = o_acc[mt][dt][r] * inv;
    }
  }
}

extern "C" void kernel_launch(void* const* d_in, const int* in_sizes, int n_in,
                              void* d_out, int out_size, void* d_ws, size_t ws_size,
                              hipStream_t stream) {
  const float* Q = (const float*)d_in[0];
  const float* K = (const float*)d_in[1];
  const float* V = (const float*)d_in[2];
  float* O = (float*)d_out;
  dim3 grid(Sdim / BLOCK_M, 4 * 16);
  attn_fwd<<<grid, 256, 0, stream>>>(Q, K, V, O);
}